// Round 8
// baseline (259.471 us; speedup 1.0000x reference)
//
#include <hip/hip_runtime.h>

#define LEAK 0.2f
#define NROW 8192
#define KDIM 128
#define MAXD 128
#define TPB  1024
#define NBLK 512

// ---- workspace layout (bytes) ----
#define OF_FLAG 0x0ul        // 4
#define OF_CNT  0x1000ul     // 8192*4
#define OF_EL1  0x10000ul    // 8192*4 each
#define OF_ER1  0x18000ul
#define OF_EL2  0x20000ul
#define OF_ER2  0x28000ul
#define OF_EL3  0x30000ul
#define OF_ER3  0x38000ul
#define OF_BAR  0x40000ul    // 4 ints: {cnt0, rel0, cnt1, rel1}, zeroed by k1
#define OF_HB1  0x100000ul   // 8192*128 bf16 (2MB)
#define OF_HB2  0x300000ul   // 8192*128 bf16 (2MB)
#define OF_HB3  0x500000ul   // 8192*64  bf16 (1MB)
#define OF_NBR  0x700000ul   // 8192*128 u16  (2MB)

typedef __attribute__((ext_vector_type(8))) short bf16x8;
typedef __attribute__((ext_vector_type(4))) float f32x4;

__device__ __forceinline__ float b2f(unsigned short u) {
  return __uint_as_float(((unsigned)u) << 16);
}
__device__ __forceinline__ unsigned short f2b(float f) {
  unsigned u = __float_as_uint(f);
  return (unsigned short)((u + 0x7FFFu + ((u >> 16) & 1u)) >> 16);
}
__device__ __forceinline__ float ld_any(const void* p, long i, int isb) {
  return isb ? b2f(((const unsigned short*)p)[i]) : ((const float*)p)[i];
}

// ---- per-block dtype probe over the SAME first 64KB of adj (L2/L3 broadcast) ----
__device__ __forceinline__ int detect_isb(const void* adj, int* sflag) {
  const uint4* a4 = (const uint4*)adj;
  if (threadIdx.x == 0) *sflag = 0;
  __syncthreads();
  unsigned any = 0;
  #pragma unroll
  for (int i = 0; i < 4; ++i) {
    uint4 v = a4[threadIdx.x + i * TPB];
    any |= (v.x | v.y | v.z | v.w);
  }
  if (any & 0xFFFFu) atomicOr(sflag, 1);
  __syncthreads();
  return *sflag;
}

// ---- hand-rolled grid barrier (requires all NBLK blocks co-resident: coop launch) ----
// Release: agent fence (drains stores + L2 writeback) before arrive.
// Wait: rep thread polls release flag with s_sleep backoff (no fabric flooding).
__device__ __forceinline__ void grid_barrier(int* cnt, int* rel) {
  __syncthreads();
  if (threadIdx.x == 0) {
    __threadfence();
    int old = __hip_atomic_fetch_add(cnt, 1, __ATOMIC_ACQ_REL, __HIP_MEMORY_SCOPE_AGENT);
    if (old == NBLK - 1) {
      __hip_atomic_store(rel, 1, __ATOMIC_RELEASE, __HIP_MEMORY_SCOPE_AGENT);
    } else {
      while (__hip_atomic_load(rel, __ATOMIC_ACQUIRE, __HIP_MEMORY_SCOPE_AGENT) == 0)
        __builtin_amdgcn_s_sleep(8);
    }
    __threadfence();
  }
  __syncthreads();
}

// ---- load 8 consecutive elements as bf16x8 from raw input (f32 or bf16) ----
__device__ __forceinline__ bf16x8 ldA(const void* X, long off, int isb) {
  if (isb) return *(const bf16x8*)((const unsigned short*)X + off);
  const float* f = (const float*)X + off;
  float4 p0 = *(const float4*)f;
  float4 p1 = *(const float4*)(f + 4);
  bf16x8 o;
  ((unsigned short*)&o)[0] = f2b(p0.x); ((unsigned short*)&o)[1] = f2b(p0.y);
  ((unsigned short*)&o)[2] = f2b(p0.z); ((unsigned short*)&o)[3] = f2b(p0.w);
  ((unsigned short*)&o)[4] = f2b(p1.x); ((unsigned short*)&o)[5] = f2b(p1.y);
  ((unsigned short*)&o)[6] = f2b(p1.z); ((unsigned short*)&o)[7] = f2b(p1.w);
  return o;
}

// ---- ballot-packed emit of one uint4 worth of adjacency ----
__device__ __forceinline__ void emit_f32(uint4 v, int cb, int& cnt, unsigned short* nb,
                                         unsigned long long ltm) {
  unsigned u[4] = {v.x, v.y, v.z, v.w};
  #pragma unroll
  for (int q = 0; q < 4; ++q) {
    int nz = u[q] != 0;
    unsigned long long m = __ballot(nz);
    if (nz) { int p = cnt + __popcll(m & ltm); if (p < MAXD) nb[p] = (unsigned short)(cb + q); }
    cnt += __popcll(m);
  }
}
__device__ __forceinline__ void emit_b16(uint4 v, int cb, int& cnt, unsigned short* nb,
                                         unsigned long long ltm) {
  unsigned u[4] = {v.x, v.y, v.z, v.w};
  #pragma unroll
  for (int q = 0; q < 4; ++q)
    #pragma unroll
    for (int k = 0; k < 2; ++k) {
      int nz = ((u[q] >> (16 * k)) & 0xFFFFu) != 0;
      unsigned long long m = __ballot(nz);
      if (nz) { int p = cnt + __popcll(m & ltm); if (p < MAXD) nb[p] = (unsigned short)(cb + q * 2 + k); }
      cnt += __popcll(m);
    }
}

// ---- neighbor list for one row (one wave), 4-deep load batching ----
__device__ __forceinline__ void nbrs_body(const void* adj, unsigned short* nbr, int* cnts,
                                          int isb, int row, int lane) {
  unsigned long long ltm = (1ull << lane) - 1ull;
  unsigned short* nb = nbr + (long)row * MAXD;
  int cnt = 0;
  if (isb) {
    const uint4* base = (const uint4*)((const char*)adj + (long)row * (NROW * 2));
    #pragma unroll 1
    for (int t = 0; t < 16; t += 4) {
      uint4 v0 = base[(t + 0) * 64 + lane];
      uint4 v1 = base[(t + 1) * 64 + lane];
      uint4 v2 = base[(t + 2) * 64 + lane];
      uint4 v3 = base[(t + 3) * 64 + lane];
      emit_b16(v0, (t + 0) * 512 + lane * 8, cnt, nb, ltm);
      emit_b16(v1, (t + 1) * 512 + lane * 8, cnt, nb, ltm);
      emit_b16(v2, (t + 2) * 512 + lane * 8, cnt, nb, ltm);
      emit_b16(v3, (t + 3) * 512 + lane * 8, cnt, nb, ltm);
    }
  } else {
    const uint4* base = (const uint4*)((const char*)adj + (long)row * (NROW * 4));
    #pragma unroll 1
    for (int t = 0; t < 32; t += 4) {
      uint4 v0 = base[(t + 0) * 64 + lane];
      uint4 v1 = base[(t + 1) * 64 + lane];
      uint4 v2 = base[(t + 2) * 64 + lane];
      uint4 v3 = base[(t + 3) * 64 + lane];
      emit_f32(v0, (t + 0) * 256 + lane * 4, cnt, nb, ltm);
      emit_f32(v1, (t + 1) * 256 + lane * 4, cnt, nb, ltm);
      emit_f32(v2, (t + 2) * 256 + lane * 4, cnt, nb, ltm);
      emit_f32(v3, (t + 3) * 256 + lane * 4, cnt, nb, ltm);
    }
  }
  if (lane == 0) cnts[row] = (cnt < MAXD ? cnt : MAXD);
}

// ---- masked-softmax aggregation for one row (one wave); returns relu'd features ----
template<int FIN>
__device__ __forceinline__ float2 agg_row(const void* HBv, const float* ER, float eli,
                                          const unsigned short* nb, int cnt, int lane) {
  const unsigned* HBU = (const unsigned*)HBv;
  const unsigned short* HBS = (const unsigned short*)HBv;
  float acc0 = 0.f, acc1 = 0.f, den = 0.f;
  for (int t0 = 0; t0 < cnt; t0 += 64) {
    int nrem = min(64, cnt - t0);
    int j = 0; float wv = 0.f;
    if (lane < nrem) { j = nb[t0 + lane]; wv = expf(eli + ER[j]); }
    int t = 0;
    for (; t + 4 <= nrem; t += 4) {
      float w0 = __shfl(wv, t),     w1 = __shfl(wv, t + 1);
      float w2 = __shfl(wv, t + 2), w3 = __shfl(wv, t + 3);
      int j0 = __shfl(j, t),     j1 = __shfl(j, t + 1);
      int j2 = __shfl(j, t + 2), j3 = __shfl(j, t + 3);
      den += (w0 + w1) + (w2 + w3);
      if (FIN == 128) {
        unsigned h0 = HBU[(long)j0 * 64 + lane], h1 = HBU[(long)j1 * 64 + lane];
        unsigned h2 = HBU[(long)j2 * 64 + lane], h3 = HBU[(long)j3 * 64 + lane];
        acc0 += w0 * b2f((unsigned short)h0) + w1 * b2f((unsigned short)h1)
              + w2 * b2f((unsigned short)h2) + w3 * b2f((unsigned short)h3);
        acc1 += w0 * b2f((unsigned short)(h0 >> 16)) + w1 * b2f((unsigned short)(h1 >> 16))
              + w2 * b2f((unsigned short)(h2 >> 16)) + w3 * b2f((unsigned short)(h3 >> 16));
      } else {
        float h0 = b2f(HBS[(long)j0 * 64 + lane]), h1 = b2f(HBS[(long)j1 * 64 + lane]);
        float h2 = b2f(HBS[(long)j2 * 64 + lane]), h3 = b2f(HBS[(long)j3 * 64 + lane]);
        acc0 += w0 * h0 + w1 * h1 + w2 * h2 + w3 * h3;
      }
    }
    for (; t < nrem; ++t) {
      float wt = __shfl(wv, t);
      int jt = __shfl(j, t);
      den += wt;
      if (FIN == 128) {
        unsigned hv = HBU[(long)jt * 64 + lane];
        acc0 += wt * b2f((unsigned short)hv);
        acc1 += wt * b2f((unsigned short)(hv >> 16));
      } else {
        acc0 += wt * b2f(HBS[(long)jt * 64 + lane]);
      }
    }
  }
  float inv = (den > 0.f) ? 1.f / den : 0.f;
  float v0 = acc0 * inv; v0 = v0 > 0.f ? v0 : 0.f;
  float v1 = acc1 * inv; v1 = v1 > 0.f ? v1 : 0.f;
  return make_float2(v0, v1);
}

// ---- 16-row GEMM tile, wave w owns col tile w (w<NCT); no internal barrier ----
template<int NCT, int AMODE>
__device__ __forceinline__ void gemm_compute(const void* Xg, const unsigned* aT,
    const void* W, const void* bia, const void* aW, unsigned short* HBo,
    float (*sEL)[16], float (*sER)[16], int isb, int row0, int w, int lane) {
  if (w >= NCT) return;
  constexpr int FOUT = NCT * 16;
  int r = lane & 15;
  int k0 = (lane >> 4) * 8;
  f32x4 acc = {0.f, 0.f, 0.f, 0.f};
  #pragma unroll
  for (int kb = 0; kb < KDIM; kb += 32) {
    bf16x8 a;
    if (AMODE == 1) {
      a = ldA(Xg, (long)(row0 + r) * KDIM + k0 + kb, isb);
    } else {
      int cb = ((k0 + kb) >> 1) ^ ((r & 7) << 2);
      a = *(const bf16x8*)(aT + r * 64 + cb);
    }
    bf16x8 bfr = ldA(W, (long)(w * 16 + r) * KDIM + k0 + kb, isb);
    acc = __builtin_amdgcn_mfma_f32_16x16x32_bf16(a, bfr, acc, 0, 0, 0);
  }
  int colg = w * 16 + r;
  float bb = ld_any(bia, colg, isb);
  float al = ld_any(aW, colg, isb);
  float ar = ld_any(aW, FOUT + colg, isb);
  #pragma unroll
  for (int j = 0; j < 4; ++j) {
    int rloc = (lane >> 4) * 4 + j;
    float v = acc[j] + bb;
    v = v > 0.f ? v : LEAK * v;
    HBo[(long)(row0 + rloc) * FOUT + colg] = f2b(v);
    float tl = v * al, tr = v * ar;
    #pragma unroll
    for (int m = 1; m < 16; m <<= 1) { tl += __shfl_xor(tl, m); tr += __shfl_xor(tr, m); }
    if (r == 0) { sEL[w][rloc] = tl; sER[w][rloc] = tr; }
  }
}

template<int NCT>
__device__ __forceinline__ void elr_reduce(float* ELo, float* ERo,
    float (*sEL)[16], float (*sER)[16], int row0) {
  if (threadIdx.x < 16) {
    float sl = 0.f, sr = 0.f;
    #pragma unroll
    for (int q = 0; q < NCT; ++q) { sl += sEL[q][threadIdx.x]; sr += sER[q][threadIdx.x]; }
    ELo[row0 + threadIdx.x] = sl;
    ERo[row0 + threadIdx.x] = sr;
  }
}

// ---- phase bodies shared by fused + fallback kernels ----
__device__ __forceinline__ void phaseA(const void* W1, const void* b1, const void* aW1,
    const void* ab0, char* ws, unsigned* aTile, float (*sEL)[16], float (*sER)[16],
    int isb, int w, int lane, int row0) {
  int row = row0 + w;
  float abv = ld_any(ab0, 0, isb);
  float2 v = agg_row<128>(ws + OF_HB1, (const float*)(ws + OF_ER1),
                          ((const float*)(ws + OF_EL1))[row] + abv,
                          (const unsigned short*)(ws + OF_NBR) + (long)row * MAXD,
                          ((const int*)(ws + OF_CNT))[row], lane);
  aTile[w * 64 + (lane ^ ((w & 7) << 2))] = ((unsigned)f2b(v.y) << 16) | (unsigned)f2b(v.x);
  __syncthreads();
  gemm_compute<8, 0>(nullptr, aTile, W1, b1, aW1,
                     (unsigned short*)(ws + OF_HB2), sEL, sER, isb, row0, w, lane);
  __syncthreads();
  elr_reduce<8>((float*)(ws + OF_EL2), (float*)(ws + OF_ER2), sEL, sER, row0);
}
__device__ __forceinline__ void phaseB(const void* W2, const void* b2, const void* aW2,
    const void* ab1, char* ws, unsigned* aTile, float (*sEL)[16], float (*sER)[16],
    int isb, int w, int lane, int row0) {
  int row = row0 + w;
  float abv = ld_any(ab1, 0, isb);
  float2 v = agg_row<128>(ws + OF_HB2, (const float*)(ws + OF_ER2),
                          ((const float*)(ws + OF_EL2))[row] + abv,
                          (const unsigned short*)(ws + OF_NBR) + (long)row * MAXD,
                          ((const int*)(ws + OF_CNT))[row], lane);
  aTile[w * 64 + (lane ^ ((w & 7) << 2))] = ((unsigned)f2b(v.y) << 16) | (unsigned)f2b(v.x);
  __syncthreads();
  gemm_compute<4, 0>(nullptr, aTile, W2, b2, aW2,
                     (unsigned short*)(ws + OF_HB3), sEL, sER, isb, row0, w, lane);
  __syncthreads();
  elr_reduce<4>((float*)(ws + OF_EL3), (float*)(ws + OF_ER3), sEL, sER, row0);
}
__device__ __forceinline__ void phaseC(const void* ab2, char* ws, void* out,
    int isb, int w, int lane, int row0) {
  int row = row0 + w;
  float abv = ld_any(ab2, 0, isb);
  float2 v = agg_row<64>(ws + OF_HB3, (const float*)(ws + OF_ER3),
                         ((const float*)(ws + OF_EL3))[row] + abv,
                         (const unsigned short*)(ws + OF_NBR) + (long)row * MAXD,
                         ((const int*)(ws + OF_CNT))[row], lane);
  if (isb) ((unsigned short*)out)[(long)row * 64 + lane] = f2b(v.x);
  else     ((float*)out)[(long)row * 64 + lane] = v.x;
}

// ==== K1: dtype detect + barrier-state reset + nbr scan + layer-1 gemm + el/er ====
__global__ __launch_bounds__(TPB, 8) void k1(const void* __restrict__ adj,
    const void* __restrict__ x, const void* __restrict__ W0,
    const void* __restrict__ b0, const void* __restrict__ aW0, char* __restrict__ ws) {
  __shared__ float sEL[8][16], sER[8][16];
  __shared__ int sflag;
  int isb = detect_isb(adj, &sflag);
  if (threadIdx.x == 0) {
    *(int*)(ws + OF_FLAG) = isb;
    if (blockIdx.x == 0) {            // reset grid-barrier state for this call
      int* bar = (int*)(ws + OF_BAR);
      bar[0] = bar[1] = bar[2] = bar[3] = 0;
    }
  }
  int w = threadIdx.x >> 6, lane = threadIdx.x & 63, row0 = blockIdx.x * 16;
  nbrs_body(adj, (unsigned short*)(ws + OF_NBR), (int*)(ws + OF_CNT), isb, row0 + w, lane);
  gemm_compute<8, 1>(x, nullptr, W0, b0, aW0,
                     (unsigned short*)(ws + OF_HB1), sEL, sER, isb, row0, w, lane);
  __syncthreads();
  elr_reduce<8>((float*)(ws + OF_EL1), (float*)(ws + OF_ER1), sEL, sER, row0);
}

// ==== KF: fused layers 2-4 with hand-rolled grid barriers (coop-launched) ====
__global__ __launch_bounds__(TPB, 8) void kf(const void* W1, const void* b1,
    const void* aW1, const void* ab0, const void* W2, const void* b2,
    const void* aW2, const void* ab1, const void* ab2, char* ws, void* out) {
  __shared__ unsigned aTile[16 * 64];
  __shared__ float sEL[8][16], sER[8][16];
  int isb = *(const int*)(ws + OF_FLAG);
  int w = threadIdx.x >> 6, lane = threadIdx.x & 63, row0 = blockIdx.x * 16;
  int* bar = (int*)(ws + OF_BAR);
  phaseA(W1, b1, aW1, ab0, ws, aTile, sEL, sER, isb, w, lane, row0);
  grid_barrier(bar + 0, bar + 1);
  phaseB(W2, b2, aW2, ab1, ws, aTile, sEL, sER, isb, w, lane, row0);
  grid_barrier(bar + 2, bar + 3);
  phaseC(ab2, ws, out, isb, w, lane, row0);
}

// ==== fallback: phases as separate kernels (round-7 proven path) ====
__global__ __launch_bounds__(TPB, 8) void k2(const void* __restrict__ W1,
    const void* __restrict__ b1, const void* __restrict__ aW1,
    const void* __restrict__ ab0, char* __restrict__ ws) {
  __shared__ unsigned aTile[16 * 64];
  __shared__ float sEL[8][16], sER[8][16];
  int isb = *(const int*)(ws + OF_FLAG);
  phaseA(W1, b1, aW1, ab0, ws, aTile, sEL, sER, isb,
         threadIdx.x >> 6, threadIdx.x & 63, blockIdx.x * 16);
}
__global__ __launch_bounds__(TPB, 8) void k3(const void* __restrict__ W2,
    const void* __restrict__ b2, const void* __restrict__ aW2,
    const void* __restrict__ ab1, char* __restrict__ ws) {
  __shared__ unsigned aTile[16 * 64];
  __shared__ float sEL[8][16], sER[8][16];
  int isb = *(const int*)(ws + OF_FLAG);
  phaseB(W2, b2, aW2, ab1, ws, aTile, sEL, sER, isb,
         threadIdx.x >> 6, threadIdx.x & 63, blockIdx.x * 16);
}
__global__ __launch_bounds__(TPB, 8) void k4(const void* __restrict__ ab2,
    char* __restrict__ ws, void* __restrict__ out) {
  int isb = *(const int*)(ws + OF_FLAG);
  phaseC(ab2, ws, out, isb, threadIdx.x >> 6, threadIdx.x & 63, blockIdx.x * 16);
}

extern "C" void kernel_launch(void* const* d_in, const int* in_sizes, int n_in,
                              void* d_out, int out_size, void* d_ws, size_t ws_size,
                              hipStream_t stream) {
  char* ws = (char*)d_ws;
  const void* x   = d_in[0];
  const void* adj = d_in[1];
  const void* W0 = d_in[2];  const void* b0 = d_in[3];  const void* aW0 = d_in[4];  const void* ab0 = d_in[5];
  const void* W1 = d_in[6];  const void* b1 = d_in[7];  const void* aW1 = d_in[8];  const void* ab1 = d_in[9];
  const void* W2 = d_in[10]; const void* b2 = d_in[11]; const void* aW2 = d_in[12]; const void* ab2 = d_in[13];
  void* outp = d_out;

  k1<<<NBLK, TPB, 0, stream>>>(adj, x, W0, b0, aW0, ws);

  int dev = 0, coop = 0;
  (void)hipGetDevice(&dev);
  (void)hipDeviceGetAttribute(&coop, hipDeviceAttributeCooperativeLaunch, dev);
  bool ok = false;
  if (coop) {
    void* args[11] = {(void*)&W1, (void*)&b1, (void*)&aW1, (void*)&ab0,
                      (void*)&W2, (void*)&b2, (void*)&aW2, (void*)&ab1,
                      (void*)&ab2, (void*)&ws, (void*)&outp};
    hipError_t e = hipLaunchCooperativeKernel((void*)kf, dim3(NBLK), dim3(TPB),
                                              args, 0, stream);
    ok = (e == hipSuccess);
    if (!ok) (void)hipGetLastError();
  }
  if (!ok) {
    k2<<<NBLK, TPB, 0, stream>>>(W1, b1, aW1, ab0, ws);
    k3<<<NBLK, TPB, 0, stream>>>(W2, b2, aW2, ab1, ws);
    k4<<<NBLK, TPB, 0, stream>>>(ab2, ws, outp);
  }
}

// Round 9
// 92.294 us; speedup vs baseline: 2.8114x; 2.8114x over previous
//
#include <hip/hip_runtime.h>

#define LEAK 0.2f
#define NROW 8192
#define KDIM 128
#define MAXD 128
#define TPB  1024
#define NBLK 512

// ---- workspace layout (bytes) ----
#define OF_FLAG 0x0ul        // 4
#define OF_CNT  0x1000ul     // 8192*4
#define OF_EL1  0x10000ul    // 8192*4 each
#define OF_ER1  0x18000ul
#define OF_EL2  0x20000ul
#define OF_ER2  0x28000ul
#define OF_EL3  0x30000ul
#define OF_ER3  0x38000ul
#define OF_HB1  0x100000ul   // 8192*128 bf16 (2MB)
#define OF_HB2  0x300000ul   // 8192*128 bf16 (2MB)
#define OF_HB3  0x500000ul   // 8192*64  bf16 (1MB)
#define OF_NBR  0x700000ul   // 8192*128 u16  (2MB)

typedef __attribute__((ext_vector_type(8))) short bf16x8;
typedef __attribute__((ext_vector_type(4))) float f32x4;

__device__ __forceinline__ float b2f(unsigned short u) {
  return __uint_as_float(((unsigned)u) << 16);
}
__device__ __forceinline__ unsigned short f2b(float f) {
  unsigned u = __float_as_uint(f);
  return (unsigned short)((u + 0x7FFFu + ((u >> 16) & 1u)) >> 16);
}
__device__ __forceinline__ float ld_any(const void* p, long i, int isb) {
  return isb ? b2f(((const unsigned short*)p)[i]) : ((const float*)p)[i];
}

// ---- per-block dtype probe over the SAME first 64KB of adj (L2/L3 broadcast) ----
// f32 0.0/1.0 dwords have structurally-zero low-16 bits; bf16 pairs leak 0x3F80.
__device__ __forceinline__ int detect_isb(const void* adj, int* sflag) {
  const uint4* a4 = (const uint4*)adj;
  if (threadIdx.x == 0) *sflag = 0;
  __syncthreads();
  unsigned any = 0;
  #pragma unroll
  for (int i = 0; i < 4; ++i) {
    uint4 v = a4[threadIdx.x + i * TPB];
    any |= (v.x | v.y | v.z | v.w);
  }
  if (any & 0xFFFFu) atomicOr(sflag, 1);
  __syncthreads();
  return *sflag;
}

// ---- load 8 consecutive elements as bf16x8 from raw input (f32 or bf16) ----
__device__ __forceinline__ bf16x8 ldA(const void* X, long off, int isb) {
  if (isb) return *(const bf16x8*)((const unsigned short*)X + off);
  const float* f = (const float*)X + off;
  float4 p0 = *(const float4*)f;
  float4 p1 = *(const float4*)(f + 4);
  bf16x8 o;
  ((unsigned short*)&o)[0] = f2b(p0.x); ((unsigned short*)&o)[1] = f2b(p0.y);
  ((unsigned short*)&o)[2] = f2b(p0.z); ((unsigned short*)&o)[3] = f2b(p0.w);
  ((unsigned short*)&o)[4] = f2b(p1.x); ((unsigned short*)&o)[5] = f2b(p1.y);
  ((unsigned short*)&o)[6] = f2b(p1.z); ((unsigned short*)&o)[7] = f2b(p1.w);
  return o;
}

// ---- ballot-packed emit of one uint4 worth of adjacency ----
__device__ __forceinline__ void emit_f32(uint4 v, int cb, int& cnt, unsigned short* nb,
                                         unsigned long long ltm) {
  unsigned u[4] = {v.x, v.y, v.z, v.w};
  #pragma unroll
  for (int q = 0; q < 4; ++q) {
    int nz = u[q] != 0;
    unsigned long long m = __ballot(nz);
    if (nz) { int p = cnt + __popcll(m & ltm); if (p < MAXD) nb[p] = (unsigned short)(cb + q); }
    cnt += __popcll(m);
  }
}
__device__ __forceinline__ void emit_b16(uint4 v, int cb, int& cnt, unsigned short* nb,
                                         unsigned long long ltm) {
  unsigned u[4] = {v.x, v.y, v.z, v.w};
  #pragma unroll
  for (int q = 0; q < 4; ++q)
    #pragma unroll
    for (int k = 0; k < 2; ++k) {
      int nz = ((u[q] >> (16 * k)) & 0xFFFFu) != 0;
      unsigned long long m = __ballot(nz);
      if (nz) { int p = cnt + __popcll(m & ltm); if (p < MAXD) nb[p] = (unsigned short)(cb + q * 2 + k); }
      cnt += __popcll(m);
    }
}

// ---- neighbor list for one row (one wave), 8-deep load batching (MLP) ----
__device__ __forceinline__ void nbrs_body(const void* adj, unsigned short* nbr, int* cnts,
                                          int isb, int row, int lane) {
  unsigned long long ltm = (1ull << lane) - 1ull;
  unsigned short* nb = nbr + (long)row * MAXD;
  int cnt = 0;
  if (isb) {
    const uint4* base = (const uint4*)((const char*)adj + (long)row * (NROW * 2));
    #pragma unroll 1
    for (int t = 0; t < 16; t += 8) {
      uint4 v[8];
      #pragma unroll
      for (int q = 0; q < 8; ++q) v[q] = base[(t + q) * 64 + lane];
      #pragma unroll
      for (int q = 0; q < 8; ++q) emit_b16(v[q], (t + q) * 512 + lane * 8, cnt, nb, ltm);
    }
  } else {
    const uint4* base = (const uint4*)((const char*)adj + (long)row * (NROW * 4));
    #pragma unroll 1
    for (int t = 0; t < 32; t += 8) {
      uint4 v[8];
      #pragma unroll
      for (int q = 0; q < 8; ++q) v[q] = base[(t + q) * 64 + lane];
      #pragma unroll
      for (int q = 0; q < 8; ++q) emit_f32(v[q], (t + q) * 256 + lane * 4, cnt, nb, ltm);
    }
  }
  if (lane == 0) cnts[row] = (cnt < MAXD ? cnt : MAXD);
}

// ---- masked-softmax aggregation for one row (one wave); returns relu'd features ----
// FIN=128: lane holds features (2*lane, 2*lane+1).  FIN=64: lane holds feature lane.
template<int FIN>
__device__ __forceinline__ float2 agg_row(const void* HBv, const float* ER, float eli,
                                          const unsigned short* nb, int cnt, int lane) {
  const unsigned* HBU = (const unsigned*)HBv;
  const unsigned short* HBS = (const unsigned short*)HBv;
  float acc0 = 0.f, acc1 = 0.f, den = 0.f;
  for (int t0 = 0; t0 < cnt; t0 += 64) {
    int nrem = min(64, cnt - t0);
    int j = 0; float wv = 0.f;
    if (lane < nrem) { j = nb[t0 + lane]; wv = expf(eli + ER[j]); }
    int t = 0;
    // 8-deep batches: 8 independent 256B gathers in flight
    for (; t + 8 <= nrem; t += 8) {
      float wt[8]; int jt[8];
      #pragma unroll
      for (int q = 0; q < 8; ++q) { wt[q] = __shfl(wv, t + q); jt[q] = __shfl(j, t + q); }
      if (FIN == 128) {
        unsigned h[8];
        #pragma unroll
        for (int q = 0; q < 8; ++q) h[q] = HBU[(long)jt[q] * 64 + lane];
        #pragma unroll
        for (int q = 0; q < 8; ++q) {
          den  += wt[q];
          acc0 += wt[q] * b2f((unsigned short)h[q]);
          acc1 += wt[q] * b2f((unsigned short)(h[q] >> 16));
        }
      } else {
        float h[8];
        #pragma unroll
        for (int q = 0; q < 8; ++q) h[q] = b2f(HBS[(long)jt[q] * 64 + lane]);
        #pragma unroll
        for (int q = 0; q < 8; ++q) { den += wt[q]; acc0 += wt[q] * h[q]; }
      }
    }
    for (; t < nrem; ++t) {
      float wt = __shfl(wv, t);
      int jt = __shfl(j, t);
      den += wt;
      if (FIN == 128) {
        unsigned hv = HBU[(long)jt * 64 + lane];
        acc0 += wt * b2f((unsigned short)hv);
        acc1 += wt * b2f((unsigned short)(hv >> 16));
      } else {
        acc0 += wt * b2f(HBS[(long)jt * 64 + lane]);
      }
    }
  }
  float inv = (den > 0.f) ? 1.f / den : 0.f;
  float v0 = acc0 * inv; v0 = v0 > 0.f ? v0 : 0.f;
  float v1 = acc1 * inv; v1 = v1 > 0.f ? v1 : 0.f;
  return make_float2(v0, v1);
}

// ---- 16-row GEMM tile, wave w owns col tile w (w<NCT); no internal barrier ----
template<int NCT, int AMODE>
__device__ __forceinline__ void gemm_compute(const void* Xg, const unsigned* aT,
    const void* W, const void* bia, const void* aW, unsigned short* HBo,
    float (*sEL)[16], float (*sER)[16], int isb, int row0, int w, int lane) {
  if (w >= NCT) return;
  constexpr int FOUT = NCT * 16;
  int r = lane & 15;
  int k0 = (lane >> 4) * 8;
  f32x4 acc = {0.f, 0.f, 0.f, 0.f};
  #pragma unroll
  for (int kb = 0; kb < KDIM; kb += 32) {
    bf16x8 a;
    if (AMODE == 1) {
      a = ldA(Xg, (long)(row0 + r) * KDIM + k0 + kb, isb);
    } else {
      int cb = ((k0 + kb) >> 1) ^ ((r & 7) << 2);
      a = *(const bf16x8*)(aT + r * 64 + cb);
    }
    bf16x8 bfr = ldA(W, (long)(w * 16 + r) * KDIM + k0 + kb, isb);
    acc = __builtin_amdgcn_mfma_f32_16x16x32_bf16(a, bfr, acc, 0, 0, 0);
  }
  int colg = w * 16 + r;
  float bb = ld_any(bia, colg, isb);
  float al = ld_any(aW, colg, isb);
  float ar = ld_any(aW, FOUT + colg, isb);
  #pragma unroll
  for (int j = 0; j < 4; ++j) {
    int rloc = (lane >> 4) * 4 + j;
    float v = acc[j] + bb;
    v = v > 0.f ? v : LEAK * v;
    HBo[(long)(row0 + rloc) * FOUT + colg] = f2b(v);
    float tl = v * al, tr = v * ar;
    #pragma unroll
    for (int m = 1; m < 16; m <<= 1) { tl += __shfl_xor(tl, m); tr += __shfl_xor(tr, m); }
    if (r == 0) { sEL[w][rloc] = tl; sER[w][rloc] = tr; }
  }
}

template<int NCT>
__device__ __forceinline__ void elr_reduce(float* ELo, float* ERo,
    float (*sEL)[16], float (*sER)[16], int row0) {
  if (threadIdx.x < 16) {
    float sl = 0.f, sr = 0.f;
    #pragma unroll
    for (int q = 0; q < NCT; ++q) { sl += sEL[q][threadIdx.x]; sr += sER[q][threadIdx.x]; }
    ELo[row0 + threadIdx.x] = sl;
    ERo[row0 + threadIdx.x] = sr;
  }
}

// ==== K1: dtype detect + full-concurrency nbr scan + layer-1 gemm + el/er ====
__global__ __launch_bounds__(TPB, 8) void k1(const void* __restrict__ adj,
    const void* __restrict__ x, const void* __restrict__ W0,
    const void* __restrict__ b0, const void* __restrict__ aW0, char* __restrict__ ws) {
  __shared__ float sEL[8][16], sER[8][16];
  __shared__ int sflag;
  int isb = detect_isb(adj, &sflag);
  if (threadIdx.x == 0) *(int*)(ws + OF_FLAG) = isb;
  int w = threadIdx.x >> 6, lane = threadIdx.x & 63, row0 = blockIdx.x * 16;
  // all 16 waves scan one row each (full concurrency, BW-bound)
  nbrs_body(adj, (unsigned short*)(ws + OF_NBR), (int*)(ws + OF_CNT), isb, row0 + w, lane);
  // layer-1 gemm (waves 0-7; independent of the scan)
  gemm_compute<8, 1>(x, nullptr, W0, b0, aW0,
                     (unsigned short*)(ws + OF_HB1), sEL, sER, isb, row0, w, lane);
  __syncthreads();
  elr_reduce<8>((float*)(ws + OF_EL1), (float*)(ws + OF_ER1), sEL, sER, row0);
}

// ==== K2: agg layer1 -> gemm layer2 (block-local fusion via swizzled LDS tile) ====
__global__ __launch_bounds__(TPB, 8) void k2(const void* __restrict__ W1,
    const void* __restrict__ b1, const void* __restrict__ aW1,
    const void* __restrict__ ab0, char* __restrict__ ws) {
  __shared__ unsigned aTile[16 * 64];
  __shared__ float sEL[8][16], sER[8][16];
  int isb = *(const int*)(ws + OF_FLAG);
  int w = threadIdx.x >> 6, lane = threadIdx.x & 63, row0 = blockIdx.x * 16;
  int row = row0 + w;
  float abv = ld_any(ab0, 0, isb);
  float2 v = agg_row<128>(ws + OF_HB1, (const float*)(ws + OF_ER1),
                          ((const float*)(ws + OF_EL1))[row] + abv,
                          (const unsigned short*)(ws + OF_NBR) + (long)row * MAXD,
                          ((const int*)(ws + OF_CNT))[row], lane);
  aTile[w * 64 + (lane ^ ((w & 7) << 2))] = ((unsigned)f2b(v.y) << 16) | (unsigned)f2b(v.x);
  __syncthreads();
  gemm_compute<8, 0>(nullptr, aTile, W1, b1, aW1,
                     (unsigned short*)(ws + OF_HB2), sEL, sER, isb, row0, w, lane);
  __syncthreads();
  elr_reduce<8>((float*)(ws + OF_EL2), (float*)(ws + OF_ER2), sEL, sER, row0);
}

// ==== K3: agg layer2 -> gemm layer3 ====
__global__ __launch_bounds__(TPB, 8) void k3(const void* __restrict__ W2,
    const void* __restrict__ b2, const void* __restrict__ aW2,
    const void* __restrict__ ab1, char* __restrict__ ws) {
  __shared__ unsigned aTile[16 * 64];
  __shared__ float sEL[8][16], sER[8][16];
  int isb = *(const int*)(ws + OF_FLAG);
  int w = threadIdx.x >> 6, lane = threadIdx.x & 63, row0 = blockIdx.x * 16;
  int row = row0 + w;
  float abv = ld_any(ab1, 0, isb);
  float2 v = agg_row<128>(ws + OF_HB2, (const float*)(ws + OF_ER2),
                          ((const float*)(ws + OF_EL2))[row] + abv,
                          (const unsigned short*)(ws + OF_NBR) + (long)row * MAXD,
                          ((const int*)(ws + OF_CNT))[row], lane);
  aTile[w * 64 + (lane ^ ((w & 7) << 2))] = ((unsigned)f2b(v.y) << 16) | (unsigned)f2b(v.x);
  __syncthreads();
  gemm_compute<4, 0>(nullptr, aTile, W2, b2, aW2,
                     (unsigned short*)(ws + OF_HB3), sEL, sER, isb, row0, w, lane);
  __syncthreads();
  elr_reduce<4>((float*)(ws + OF_EL3), (float*)(ws + OF_ER3), sEL, sER, row0);
}

// ==== K4: agg layer3 -> d_out; fine-grained blocks (4 waves, 1 row/wave) ====
__global__ __launch_bounds__(256, 8) void k4(const void* __restrict__ ab2,
    char* __restrict__ ws, void* __restrict__ out) {
  int isb = *(const int*)(ws + OF_FLAG);
  int w = threadIdx.x >> 6, lane = threadIdx.x & 63;
  int row = blockIdx.x * 4 + w;
  float abv = ld_any(ab2, 0, isb);
  float2 v = agg_row<64>(ws + OF_HB3, (const float*)(ws + OF_ER3),
                         ((const float*)(ws + OF_EL3))[row] + abv,
                         (const unsigned short*)(ws + OF_NBR) + (long)row * MAXD,
                         ((const int*)(ws + OF_CNT))[row], lane);
  if (isb) ((unsigned short*)out)[(long)row * 64 + lane] = f2b(v.x);
  else     ((float*)out)[(long)row * 64 + lane] = v.x;
}

extern "C" void kernel_launch(void* const* d_in, const int* in_sizes, int n_in,
                              void* d_out, int out_size, void* d_ws, size_t ws_size,
                              hipStream_t stream) {
  char* ws = (char*)d_ws;
  const void* x   = d_in[0];
  const void* adj = d_in[1];
  const void* W0 = d_in[2];  const void* b0 = d_in[3];  const void* aW0 = d_in[4];  const void* ab0 = d_in[5];
  const void* W1 = d_in[6];  const void* b1 = d_in[7];  const void* aW1 = d_in[8];  const void* ab1 = d_in[9];
  const void* W2 = d_in[10]; const void* b2 = d_in[11]; const void* aW2 = d_in[12]; const void* ab2 = d_in[13];

  k1<<<NBLK, TPB, 0, stream>>>(adj, x, W0, b0, aW0, ws);
  k2<<<NBLK, TPB, 0, stream>>>(W1, b1, aW1, ab0, ws);
  k3<<<NBLK, TPB, 0, stream>>>(W2, b2, aW2, ab1, ws);
  k4<<<2048, 256, 0, stream>>>(ab2, ws, d_out);
}